// Round 2
// baseline (600.571 us; speedup 1.0000x reference)
//
#include <hip/hip_runtime.h>

#define HD 256
#define KD 512

typedef _Float16 half8 __attribute__((ext_vector_type(8)));
typedef _Float16 half4v __attribute__((ext_vector_type(4)));
typedef float floatx4 __attribute__((ext_vector_type(4)));

__device__ __forceinline__ float sigmf_(float x) { return 1.f / (1.f + __expf(-x)); }
__device__ __forceinline__ float tanhf_(float x) {
  x = fminf(fmaxf(x, -15.f), 15.f);
  float e = __expf(2.f * x);
  return (e - 1.f) / (e + 1.f);
}

// ---------------------------------------------------------------------------
// prep (parallel, 16 blocks): gate bias sums, leaf csum (=2*c_leaf), and
// leaf-level folded bias: bias2[g][n] = bsum[g][n] + W_g[n][0:256]·(2*h_leaf)
// ---------------------------------------------------------------------------
__global__ void prep_kernel(const float* __restrict__ bf_, const float* __restrict__ b_f,
                            const float* __restrict__ bi_, const float* __restrict__ b_i,
                            const float* __restrict__ bu_, const float* __restrict__ b_u,
                            const float* __restrict__ bo_, const float* __restrict__ b_o,
                            const float* __restrict__ Wf, const float* __restrict__ Wi,
                            const float* __restrict__ Wu, const float* __restrict__ Wo,
                            float* __restrict__ bsum, float* __restrict__ bias2,
                            float* __restrict__ cleaf2)
{
  __shared__ float hl2[HD];
  __shared__ float part[64][4];
  const int t = threadIdx.x;
  float sf = bf_[t] + b_f[t];
  float si = bi_[t] + b_i[t];
  float su = bu_[t] + b_u[t];
  float so = bo_[t] + b_o[t];
  float ig = 1.f / (1.f + expf(-si));
  float uu = tanhf(su);
  float cl = ig * uu;
  float hl = (1.f / (1.f + expf(-so))) * tanhf(cl);
  hl2[t] = 2.f * hl;
  if (blockIdx.x == 0) {
    bsum[t] = sf; bsum[HD + t] = si; bsum[2 * HD + t] = su; bsum[3 * HD + t] = so;
    cleaf2[t] = cl + cl;
  }
  __syncthreads();
  const int g = blockIdx.x >> 2, q = blockIdx.x & 3;
  const int nl = t >> 2, kq = t & 3;
  const float* Wg = (g == 0) ? Wf : (g == 1) ? Wi : (g == 2) ? Wu : Wo;
  const float* w = Wg + (long)(q * 64 + nl) * KD + kq * 64;
  float s = 0.f;
  for (int k = 0; k < 64; k += 4) {
    floatx4 wv = *(const floatx4*)(w + k);
    floatx4 hv = *(const floatx4*)(&hl2[kq * 64 + k]);
    s += wv[0] * hv[0] + wv[1] * hv[1] + wv[2] * hv[2] + wv[3] * hv[3];
  }
  part[nl][kq] = s;
  __syncthreads();
  if (kq == 0) {
    const int n = q * 64 + nl;
    float tot = part[nl][0] + part[nl][1] + part[nl][2] + part[nl][3];
    float bg = (g == 0) ? (bf_[n] + b_f[n]) : (g == 1) ? (bi_[n] + b_i[n])
             : (g == 2) ? (bu_[n] + b_u[n]) : (bo_[n] + b_o[n]);
    bias2[g * HD + n] = bg + tot;
  }
}

// ---------------------------------------------------------------------------
// convert the 4 gate weights (fp32, [256][512]) to f16 packed [g][256][512]
// ---------------------------------------------------------------------------
__global__ void wcvt_kernel(const float* __restrict__ Wf, const float* __restrict__ Wi,
                            const float* __restrict__ Wu, const float* __restrict__ Wo,
                            _Float16* __restrict__ Wh)
{
  int idx = (blockIdx.x * 256 + threadIdx.x) * 4;
  int g = idx >> 17;
  int rem = idx & ((1 << 17) - 1);
  const float* src = (g == 0) ? Wf : (g == 1) ? Wi : (g == 2) ? Wu : Wo;
  floatx4 v = *(const floatx4*)(src + rem);
  half4v o;
  o[0] = (_Float16)v[0]; o[1] = (_Float16)v[1]; o[2] = (_Float16)v[2]; o[3] = (_Float16)v[3];
  *(half4v*)(Wh + idx) = o;
}

// ---------------------------------------------------------------------------
// esum: pre-materialized f16 embed pair-sums, parent-indexed.
// esum[b][p][c] = embed[b][2p+1][c] + embed[b][2p+2][c], p in [0,511).
// ---------------------------------------------------------------------------
__global__ void esum_kernel(const float* __restrict__ embed, _Float16* __restrict__ esum)
{
  const int task = blockIdx.x * 256 + threadIdx.x;
  if (task >= 511 * 32) return;
  const int b = blockIdx.y;
  const int p = task >> 5, g8 = task & 31;
  const float* e0 = embed + ((long)b * 1023 + 2 * p + 1) * 256 + g8 * 8;
  const float* e1 = e0 + 256;
  floatx4 x0 = *(const floatx4*)(e0);
  floatx4 x1 = *(const floatx4*)(e0 + 4);
  floatx4 y0 = *(const floatx4*)(e1);
  floatx4 y1 = *(const floatx4*)(e1 + 4);
  half8 s;
#pragma unroll
  for (int e = 0; e < 4; ++e) { s[e] = (_Float16)(x0[e] + y0[e]); s[4 + e] = (_Float16)(x1[e] + y1[e]); }
  *(half8*)(esum + ((long)b * 511 + p) * 256 + g8 * 8) = s;
}

// ---------------------------------------------------------------------------
// level kernel, R7: barrier-free direct-register A.
//  - NO LDS. A fragments load straight from global (L2-resident after the
//    XCD-aligned grid: same-A col-blocks have ids bx + cb*2^l, 2^l%8==0 for
//    big levels -> same XCD; per-XCD footprint ~2MB A + 1MB Wh < 4MB L2).
//    Fragment addr: lane reads row m0+rh*64+mt*16+lm, k = quad*8 + ks*32
//    (16B/lane, 64B segments). Costs 2x A reads (ch-paired waves) from L2,
//    eliminates ALL barriers + all LDS bank conflicts: the kernel is one
//    straight-line load/MFMA stream the compiler pipelines with counted
//    vmcnt (no lockstep drain points -> R1's non-leaf regression gone).
//  - depth-1 rolling prefetch for BOTH A and B (proven: R5 regression
//    without B prefetch); static acc indexing only (R1-3 scratch spill).
//  - epilogue fully in-lane, unchanged.
// ---------------------------------------------------------------------------
__global__ __launch_bounds__(256, 2)
void level_kernel(const _Float16* __restrict__ hsum_in,
                  const float* __restrict__ csum_in,
                  const _Float16* __restrict__ esum,
                  const _Float16* __restrict__ Wh,
                  const float* __restrict__ bias,
                  _Float16* __restrict__ hsum_out,
                  float* __restrict__ csum_out,
                  int l, int leaf, int fin)
{
  const int cb = blockIdx.y;             // 0..7 col-block
  const int m0 = blockIdx.x * 128;       // row-group (same-A blocks share XCD)
  const int t = threadIdx.x;
  const int wave = t >> 6;
  const int lane = t & 63;
  const int lm = lane & 15;
  const int quad = lane >> 4;
  const int rh = wave >> 1;              // row half (64 rows)
  const int ch = wave & 1;               // col half (16 cols)
  const int ncol = cb * 32 + ch * 16 + lm;

  floatx4 acc[4][4] = {};                // [mt][gate]

  const _Float16* wb = Wh + (long)ncol * KD + quad * 8;
  const int msk = (1 << l) - 1;

  // Per-mt A base pointers (lane's row, lane's k-phase quad*8).
  const _Float16* ah[4];                 // hsum source (k 0..255 of W)
  const _Float16* ae[4];                 // esum source (k 256..511 of W)
#pragma unroll
  for (int mt = 0; mt < 4; ++mt) {
    const int sm = m0 + rh * 64 + mt * 16 + lm;
    const long erow = (long)(sm >> l) * 511 + msk + (sm & msk);
    ae[mt] = esum + erow * HD + quad * 8;
    ah[mt] = leaf ? ae[mt] : (hsum_in + (long)sm * HD + quad * 8);
  }

  // 8 k-steps (K=256) over one A source, B starting at k-col bk0.
  auto gemm8 = [&](const _Float16* const* a, int bk0) {
    half8 bcur[4], bnxt[4], acur[4], anxt[4];
#pragma unroll
    for (int g = 0; g < 4; ++g)
      bcur[g] = *(const half8*)(wb + (long)g * HD * KD + bk0);
#pragma unroll
    for (int mt = 0; mt < 4; ++mt)
      acur[mt] = *(const half8*)(a[mt]);
#pragma unroll
    for (int ks = 0; ks < 8; ++ks) {
      if (ks < 7) {
#pragma unroll
        for (int g = 0; g < 4; ++g)
          bnxt[g] = *(const half8*)(wb + (long)g * HD * KD + bk0 + (ks + 1) * 32);
#pragma unroll
        for (int mt = 0; mt < 4; ++mt)
          anxt[mt] = *(const half8*)(a[mt] + (ks + 1) * 32);
      }
#pragma unroll
      for (int mt = 0; mt < 4; ++mt)
#pragma unroll
        for (int g = 0; g < 4; ++g)
          acc[mt][g] = __builtin_amdgcn_mfma_f32_16x16x32_f16(acur[mt], bcur[g], acc[mt][g], 0, 0, 0);
#pragma unroll
      for (int g = 0; g < 4; ++g) bcur[g] = bnxt[g];
#pragma unroll
      for (int mt = 0; mt < 4; ++mt) acur[mt] = anxt[mt];
    }
  };

  if (!leaf) gemm8(ah, 0);               // child-h pair-sums vs W[:, 0:256]
  gemm8(ae, 256);                        // embed pair-sums vs W[:, 256:512]

  // ---------------- epilogue: fully in-lane ----------------
  const float b0 = bias[ncol];
  const float b1 = bias[HD + ncol];
  const float b2 = bias[2 * HD + ncol];
  const float b3 = bias[3 * HD + ncol];
  const float clv = leaf ? csum_in[ncol] : 0.f;

#pragma unroll
  for (int mt = 0; mt < 4; ++mt) {
    const int mg0 = m0 + rh * 64 + mt * 16 + quad * 4;
    float hv[4], cvv[4];
#pragma unroll
    for (int e = 0; e < 4; ++e) {
      float cs = leaf ? clv : csum_in[(long)(mg0 + e) * HD + ncol];
      float zf = acc[mt][0][e] + b0;
      float zi = acc[mt][1][e] + b1;
      float zu = acc[mt][2][e] + b2;
      float zo = acc[mt][3][e] + b3;
      float f = sigmf_(zf), ig = sigmf_(zi), uu = tanhf_(zu), oo = sigmf_(zo);
      float cn = ig * uu + f * cs;
      cvv[e] = cn;
      hv[e] = oo * tanhf_(cn);
    }
    if (fin) {
#pragma unroll
      for (int e = 0; e < 4; ++e)
        hsum_out[(long)(mg0 + e) * HD + ncol] = (_Float16)hv[e];
    } else {
      const long pr = mg0 >> 1;
      hsum_out[pr * HD + ncol] = (_Float16)(hv[0] + hv[1]);
      hsum_out[(pr + 1) * HD + ncol] = (_Float16)(hv[2] + hv[3]);
      csum_out[pr * HD + ncol] = cvv[0] + cvv[1];
      csum_out[(pr + 1) * HD + ncol] = cvv[2] + cvv[3];
    }
  }
}

// ---------------------------------------------------------------------------
// fused head: y=tanh(hr@W1+b1); y2=relu(hr@W2+b2)@W3+b3; out=relu((y+y2)@W4+b4)
// ---------------------------------------------------------------------------
__global__ void head_all_kernel(const _Float16* __restrict__ hr,
                                const float* __restrict__ W1, const float* __restrict__ bl1,
                                const float* __restrict__ W2, const float* __restrict__ bl2,
                                const float* __restrict__ W3, const float* __restrict__ bl3,
                                const float* __restrict__ W4, const float* __restrict__ bl4,
                                float* __restrict__ out)
{
  __shared__ float a[HD];
  __shared__ float t1s[HD];
  __shared__ float t2s[HD];
  int b = blockIdx.x, n = threadIdx.x;
  a[n] = (float)hr[b * HD + n];
  __syncthreads();
  {
    const float* w1 = W1 + n * HD;
    const float* w2 = W2 + n * HD;
    float s1 = bl1[n], s2 = bl2[n];
    for (int k = 0; k < HD; k += 4) {
      floatx4 av = *(const floatx4*)(&a[k]);
      floatx4 w1v = *(const floatx4*)(w1 + k);
      floatx4 w2v = *(const floatx4*)(w2 + k);
#pragma unroll
      for (int e = 0; e < 4; ++e) { s1 += av[e] * w1v[e]; s2 += av[e] * w2v[e]; }
    }
    t1s[n] = tanhf_(s1);
    t2s[n] = fmaxf(s2, 0.f);
  }
  __syncthreads();
  {
    const float* w3 = W3 + n * HD;
    float s3 = bl3[n];
    for (int k = 0; k < HD; k += 4) {
      floatx4 av = *(const floatx4*)(&t2s[k]);
      floatx4 wv = *(const floatx4*)(w3 + k);
#pragma unroll
      for (int e = 0; e < 4; ++e) s3 += av[e] * wv[e];
    }
    __syncthreads();
    a[n] = t1s[n] + s3;
  }
  __syncthreads();
  {
    const float* w4 = W4 + n * HD;
    float s4 = bl4[n];
    for (int k = 0; k < HD; k += 4) {
      floatx4 av = *(const floatx4*)(&a[k]);
      floatx4 wv = *(const floatx4*)(w4 + k);
#pragma unroll
      for (int e = 0; e < 4; ++e) s4 += av[e] * wv[e];
    }
    out[b * HD + n] = fmaxf(s4, 0.f);
  }
}

// ---------------------------------------------------------------------------
extern "C" void kernel_launch(void* const* d_in, const int* in_sizes, int n_in,
                              void* d_out, int out_size, void* d_ws, size_t ws_size,
                              hipStream_t stream)
{
  (void)in_sizes; (void)n_in; (void)out_size; (void)ws_size;
  const float* embed = (const float*)d_in[0];
  const float* Wf  = (const float*)d_in[1];
  const float* bf_ = (const float*)d_in[2];
  const float* b_f = (const float*)d_in[3];
  const float* Wi  = (const float*)d_in[4];
  const float* bi_ = (const float*)d_in[5];
  const float* b_i = (const float*)d_in[6];
  const float* Wu  = (const float*)d_in[7];
  const float* bu_ = (const float*)d_in[8];
  const float* b_u = (const float*)d_in[9];
  const float* Wo  = (const float*)d_in[10];
  const float* bo_ = (const float*)d_in[11];
  const float* b_o = (const float*)d_in[12];
  const float* W1  = (const float*)d_in[13];
  const float* bl1 = (const float*)d_in[14];
  const float* W2  = (const float*)d_in[15];
  const float* bl2 = (const float*)d_in[16];
  const float* W3  = (const float*)d_in[17];
  const float* bl3 = (const float*)d_in[18];
  const float* W4  = (const float*)d_in[19];
  const float* bl4 = (const float*)d_in[20];

  char* ws = (char*)d_ws;
  _Float16* Wh   = (_Float16*)(ws);                 // 1,048,576 B
  float* bsum    = (float*)(ws + 1048576);          // 4 KB
  float* bias2   = (float*)(ws + 1052672);          // 4 KB
  float* cleaf2  = (float*)(ws + 1056768);          // 1 KB
  _Float16* hr   = (_Float16*)(ws + 1057792);       // 64 KB -> end 1,123,328
  _Float16* esum = (_Float16*)(ws + 1123328);       // 33,488,896 B -> 34,612,224
  _Float16* HsA  = (_Float16*)(ws + 34612224);      // 8,388,608 -> 43,000,832
  float* CsA     = (float*)(ws + 43000832);         // 16,777,216 -> 59,778,048
  _Float16* HsB  = (_Float16*)(ws + 59778048);      // 4,194,304 -> 63,972,352
  float* CsB     = (float*)(ws + 63972352);         // 8,388,608 -> 72,360,960

  prep_kernel<<<dim3(16), dim3(256), 0, stream>>>(bf_, b_f, bi_, b_i, bu_, b_u, bo_, b_o,
                                                  Wf, Wi, Wu, Wo, bsum, bias2, cleaf2);
  wcvt_kernel<<<dim3(512), dim3(256), 0, stream>>>(Wf, Wi, Wu, Wo, Wh);
  esum_kernel<<<dim3(64, 128), dim3(256), 0, stream>>>(embed, esum);

  _Float16* hbufs[2] = {HsA, HsB};
  float* cbufs[2] = {CsA, CsB};
  int pp = 0;
  const _Float16* hin = nullptr;
  const float* cin = cleaf2;
  for (int l = 8; l >= 0; --l) {
    const int leaf = (l == 8);
    const int fin = (l == 0);
    _Float16* hout = fin ? hr : hbufs[pp];
    float* cout = cbufs[pp];
    dim3 grid(1 << l, 8);
    level_kernel<<<grid, dim3(256), 0, stream>>>(hin, cin, esum, Wh,
                                                 leaf ? bias2 : bsum,
                                                 hout, cout, l, leaf, fin);
    hin = hbufs[pp];
    cin = cbufs[pp];
    pp ^= 1;
  }

  head_all_kernel<<<dim3(128), dim3(256), 0, stream>>>(hr, W1, bl1, W2, bl2, W3, bl3,
                                                       W4, bl4, (float*)d_out);
}

// Round 3
// 485.533 us; speedup vs baseline: 1.2369x; 1.2369x over previous
//
#include <hip/hip_runtime.h>

#define HD 256
#define KD 512

typedef _Float16 half8 __attribute__((ext_vector_type(8)));
typedef _Float16 half2v __attribute__((ext_vector_type(2)));
typedef _Float16 half4v __attribute__((ext_vector_type(4)));
typedef float floatx4 __attribute__((ext_vector_type(4)));
typedef float floatx2 __attribute__((ext_vector_type(2)));

__device__ __forceinline__ float sigmf_(float x) { return 1.f / (1.f + __expf(-x)); }
__device__ __forceinline__ float tanhf_(float x) {
  x = fminf(fmaxf(x, -15.f), 15.f);
  float e = __expf(2.f * x);
  return (e - 1.f) / (e + 1.f);
}

// ---------------------------------------------------------------------------
// prep (parallel, 16 blocks): gate bias sums, leaf csum (=2*c_leaf), and
// leaf-level folded bias: bias2[g][n] = bsum[g][n] + W_g[n][0:256]·(2*h_leaf)
// ---------------------------------------------------------------------------
__global__ void prep_kernel(const float* __restrict__ bf_, const float* __restrict__ b_f,
                            const float* __restrict__ bi_, const float* __restrict__ b_i,
                            const float* __restrict__ bu_, const float* __restrict__ b_u,
                            const float* __restrict__ bo_, const float* __restrict__ b_o,
                            const float* __restrict__ Wf, const float* __restrict__ Wi,
                            const float* __restrict__ Wu, const float* __restrict__ Wo,
                            float* __restrict__ bsum, float* __restrict__ bias2,
                            float* __restrict__ cleaf2)
{
  __shared__ float hl2[HD];
  __shared__ float part[64][4];
  const int t = threadIdx.x;
  float sf = bf_[t] + b_f[t];
  float si = bi_[t] + b_i[t];
  float su = bu_[t] + b_u[t];
  float so = bo_[t] + b_o[t];
  float ig = 1.f / (1.f + expf(-si));
  float uu = tanhf(su);
  float cl = ig * uu;
  float hl = (1.f / (1.f + expf(-so))) * tanhf(cl);
  hl2[t] = 2.f * hl;
  if (blockIdx.x == 0) {
    bsum[t] = sf; bsum[HD + t] = si; bsum[2 * HD + t] = su; bsum[3 * HD + t] = so;
    cleaf2[t] = cl + cl;
  }
  __syncthreads();
  const int g = blockIdx.x >> 2, q = blockIdx.x & 3;
  const int nl = t >> 2, kq = t & 3;
  const float* Wg = (g == 0) ? Wf : (g == 1) ? Wi : (g == 2) ? Wu : Wo;
  const float* w = Wg + (long)(q * 64 + nl) * KD + kq * 64;
  float s = 0.f;
  for (int k = 0; k < 64; k += 4) {
    floatx4 wv = *(const floatx4*)(w + k);
    floatx4 hv = *(const floatx4*)(&hl2[kq * 64 + k]);
    s += wv[0] * hv[0] + wv[1] * hv[1] + wv[2] * hv[2] + wv[3] * hv[3];
  }
  part[nl][kq] = s;
  __syncthreads();
  if (kq == 0) {
    const int n = q * 64 + nl;
    float tot = part[nl][0] + part[nl][1] + part[nl][2] + part[nl][3];
    float bg = (g == 0) ? (bf_[n] + b_f[n]) : (g == 1) ? (bi_[n] + b_i[n])
             : (g == 2) ? (bu_[n] + b_u[n]) : (bo_[n] + b_o[n]);
    bias2[g * HD + n] = bg + tot;
  }
}

// ---------------------------------------------------------------------------
// convert the 4 gate weights (fp32, [256][512]) to f16 packed [g][256][512]
// ---------------------------------------------------------------------------
__global__ void wcvt_kernel(const float* __restrict__ Wf, const float* __restrict__ Wi,
                            const float* __restrict__ Wu, const float* __restrict__ Wo,
                            _Float16* __restrict__ Wh)
{
  int idx = (blockIdx.x * 256 + threadIdx.x) * 4;
  int g = idx >> 17;
  int rem = idx & ((1 << 17) - 1);
  const float* src = (g == 0) ? Wf : (g == 1) ? Wi : (g == 2) ? Wu : Wo;
  floatx4 v = *(const floatx4*)(src + rem);
  half4v o;
  o[0] = (_Float16)v[0]; o[1] = (_Float16)v[1]; o[2] = (_Float16)v[2]; o[3] = (_Float16)v[3];
  *(half4v*)(Wh + idx) = o;
}

// ---------------------------------------------------------------------------
// esum: pre-materialized f16 embed pair-sums, parent-indexed.
// esum[b][p][c] = embed[b][2p+1][c] + embed[b][2p+2][c], p in [0,511).
// Level l uses parents p = (2^l - 1) .. (2^(l+1) - 2) — a contiguous slice.
// ---------------------------------------------------------------------------
__global__ void esum_kernel(const float* __restrict__ embed, _Float16* __restrict__ esum)
{
  const int task = blockIdx.x * 256 + threadIdx.x;
  if (task >= 511 * 32) return;
  const int b = blockIdx.y;
  const int p = task >> 5, g8 = task & 31;
  const float* e0 = embed + ((long)b * 1023 + 2 * p + 1) * 256 + g8 * 8;
  const float* e1 = e0 + 256;
  floatx4 x0 = *(const floatx4*)(e0);
  floatx4 x1 = *(const floatx4*)(e0 + 4);
  floatx4 y0 = *(const floatx4*)(e1);
  floatx4 y1 = *(const floatx4*)(e1 + 4);
  half8 s;
#pragma unroll
  for (int e = 0; e < 4; ++e) { s[e] = (_Float16)(x0[e] + y0[e]); s[4 + e] = (_Float16)(x1[e] + y1[e]); }
  *(half8*)(esum + ((long)b * 511 + p) * 256 + g8 * 8) = s;
}

// ---------------------------------------------------------------------------
// level kernel, R8: exact R0 (510 us proven) structure + XCD-aligned grid.
// Block tile: 128 rows x 32 cols x ALL 4 gates; wave: 64 rows x 16 cols x 4g,
// acc[mt 4][gate 4] (static indices only!). 64 KB LDS tile, 2 staging chunks,
// depth-1 B prefetch, fully in-lane epilogue — all unchanged from R0.
// ONLY change: grid = (M/128, 8), cb = blockIdx.y. Same-A col-blocks get
// linear ids bx + cb*2^l; 2^l % 8 == 0 for l>=3 -> all 8 land on the SAME
// XCD -> per-XCD A footprint (<=2 MB slice + 1 MB Wh) is L2-resident.
// Kills the 8x cross-XCD A duplication (leaf FETCH 66 MB -> ~28 MB).
// R1 proved this helps the leaf; R1's regression came from the 32KB
// chunking (doubled barrier drains), which is NOT carried over. R2 proved
// removing LDS entirely is worse (latency-bound). 
// ---------------------------------------------------------------------------
__global__ __launch_bounds__(256, 2)
void level_kernel(const _Float16* __restrict__ hsum_in,
                  const float* __restrict__ csum_in,
                  const _Float16* __restrict__ esum,
                  const _Float16* __restrict__ Wh,
                  const float* __restrict__ bias,
                  _Float16* __restrict__ hsum_out,
                  float* __restrict__ csum_out,
                  int l, int leaf, int fin)
{
  __shared__ _Float16 As[128][256];      // 64 KB, XOR-swizzled 16B granules

  const int cb = blockIdx.y;             // 0..7 col-block (XCD-aligned)
  const int m0 = blockIdx.x * 128;       // row-group
  const int t = threadIdx.x;
  const int wave = t >> 6;
  const int lane = t & 63;
  const int lm = lane & 15;
  const int quad = lane >> 4;
  const int rh = wave >> 1;              // row half (64 rows)
  const int ch = wave & 1;               // col half (16 cols)
  const int ncol = cb * 32 + ch * 16 + lm;

  floatx4 acc[4][4] = {};                // [mt][gate]

  // staging map: 8 threads/row, lane granule-id distinct low-3 bits so the
  // XOR-swizzled LDS stores cover all 8 bank groups (conflict-free).
  const int srow0 = t >> 3;              // 0..31, +32 per pass
  const int sg = t & 7;                  // granule low bits

  const _Float16* wb = Wh + (long)ncol * KD + quad * 8;

  auto gemm_chunk = [&](int kbase) {
    half8 bcur[4], bnxt[4];
#pragma unroll
    for (int g = 0; g < 4; ++g)
      bcur[g] = *(const half8*)(wb + (long)g * HD * KD + kbase);
#pragma unroll
    for (int ks = 0; ks < 8; ++ks) {
      if (ks < 7) {
#pragma unroll
        for (int g = 0; g < 4; ++g)
          bnxt[g] = *(const half8*)(wb + (long)g * HD * KD + kbase + (ks + 1) * 32);
      }
      half8 afr[4];
#pragma unroll
      for (int mt = 0; mt < 4; ++mt) {
        int row = rh * 64 + mt * 16 + lm;
        afr[mt] = *(const half8*)(&As[row][(((ks * 4 + quad) ^ (row & 7)) * 8)]);
      }
#pragma unroll
      for (int mt = 0; mt < 4; ++mt)
#pragma unroll
        for (int g = 0; g < 4; ++g)
          acc[mt][g] = __builtin_amdgcn_mfma_f32_16x16x32_f16(afr[mt], bcur[g], acc[mt][g], 0, 0, 0);
#pragma unroll
      for (int g = 0; g < 4; ++g) bcur[g] = bnxt[g];
    }
  };

  const int msk = (1 << l) - 1;

  if (!leaf) {
    // chunk 0: pre-summed child h (k 0..255) — pure f16 copy
#pragma unroll
    for (int p = 0; p < 4; ++p) {
      const int r = srow0 + 32 * p;
      const _Float16* src = hsum_in + (long)(m0 + r) * HD;
#pragma unroll
      for (int q = 0; q < 4; ++q) {
        int g8 = sg + 8 * q;
        *(half8*)(&As[r][((g8 ^ (r & 7)) * 8)]) = *(const half8*)(src + g8 * 8);
      }
    }
    __syncthreads();
    gemm_chunk(0);
    __syncthreads();
  }

  // chunk 1: embed pair-sums from esum (k 256..511 of W) — pure f16 copy
  {
#pragma unroll
    for (int p = 0; p < 4; ++p) {
      const int r = srow0 + 32 * p;
      const int sm = m0 + r;
      const long erow = (long)(sm >> l) * 511 + msk + (sm & msk);
      const _Float16* src = esum + erow * HD;
#pragma unroll
      for (int q = 0; q < 4; ++q) {
        int g8 = sg + 8 * q;
        *(half8*)(&As[r][((g8 ^ (r & 7)) * 8)]) = *(const half8*)(src + g8 * 8);
      }
    }
  }
  __syncthreads();
  gemm_chunk(256);

  // ---------------- epilogue: fully in-lane ----------------
  const float b0 = bias[ncol];
  const float b1 = bias[HD + ncol];
  const float b2 = bias[2 * HD + ncol];
  const float b3 = bias[3 * HD + ncol];
  const float clv = leaf ? csum_in[ncol] : 0.f;

#pragma unroll
  for (int mt = 0; mt < 4; ++mt) {
    const int mg0 = m0 + rh * 64 + mt * 16 + quad * 4;
    float hv[4], cvv[4];
#pragma unroll
    for (int e = 0; e < 4; ++e) {
      float cs = leaf ? clv : csum_in[(long)(mg0 + e) * HD + ncol];
      float zf = acc[mt][0][e] + b0;
      float zi = acc[mt][1][e] + b1;
      float zu = acc[mt][2][e] + b2;
      float zo = acc[mt][3][e] + b3;
      float f = sigmf_(zf), ig = sigmf_(zi), uu = tanhf_(zu), oo = sigmf_(zo);
      float cn = ig * uu + f * cs;
      cvv[e] = cn;
      hv[e] = oo * tanhf_(cn);
    }
    if (fin) {
#pragma unroll
      for (int e = 0; e < 4; ++e)
        hsum_out[(long)(mg0 + e) * HD + ncol] = (_Float16)hv[e];
    } else {
      const long pr = mg0 >> 1;
      hsum_out[pr * HD + ncol] = (_Float16)(hv[0] + hv[1]);
      hsum_out[(pr + 1) * HD + ncol] = (_Float16)(hv[2] + hv[3]);
      csum_out[pr * HD + ncol] = cvv[0] + cvv[1];
      csum_out[(pr + 1) * HD + ncol] = cvv[2] + cvv[3];
    }
  }
}

// ---------------------------------------------------------------------------
// fused head: y=tanh(hr@W1+b1); y2=relu(hr@W2+b2)@W3+b3; out=relu((y+y2)@W4+b4)
// ---------------------------------------------------------------------------
__global__ void head_all_kernel(const _Float16* __restrict__ hr,
                                const float* __restrict__ W1, const float* __restrict__ bl1,
                                const float* __restrict__ W2, const float* __restrict__ bl2,
                                const float* __restrict__ W3, const float* __restrict__ bl3,
                                const float* __restrict__ W4, const float* __restrict__ bl4,
                                float* __restrict__ out)
{
  __shared__ float a[HD];
  __shared__ float t1s[HD];
  __shared__ float t2s[HD];
  int b = blockIdx.x, n = threadIdx.x;
  a[n] = (float)hr[b * HD + n];
  __syncthreads();
  {
    const float* w1 = W1 + n * HD;
    const float* w2 = W2 + n * HD;
    float s1 = bl1[n], s2 = bl2[n];
    for (int k = 0; k < HD; k += 4) {
      floatx4 av = *(const floatx4*)(&a[k]);
      floatx4 w1v = *(const floatx4*)(w1 + k);
      floatx4 w2v = *(const floatx4*)(w2 + k);
#pragma unroll
      for (int e = 0; e < 4; ++e) { s1 += av[e] * w1v[e]; s2 += av[e] * w2v[e]; }
    }
    t1s[n] = tanhf_(s1);
    t2s[n] = fmaxf(s2, 0.f);
  }
  __syncthreads();
  {
    const float* w3 = W3 + n * HD;
    float s3 = bl3[n];
    for (int k = 0; k < HD; k += 4) {
      floatx4 av = *(const floatx4*)(&t2s[k]);
      floatx4 wv = *(const floatx4*)(w3 + k);
#pragma unroll
      for (int e = 0; e < 4; ++e) s3 += av[e] * wv[e];
    }
    __syncthreads();
    a[n] = t1s[n] + s3;
  }
  __syncthreads();
  {
    const float* w4 = W4 + n * HD;
    float s4 = bl4[n];
    for (int k = 0; k < HD; k += 4) {
      floatx4 av = *(const floatx4*)(&a[k]);
      floatx4 wv = *(const floatx4*)(w4 + k);
#pragma unroll
      for (int e = 0; e < 4; ++e) s4 += av[e] * wv[e];
    }
    out[b * HD + n] = fmaxf(s4, 0.f);
  }
}

// ---------------------------------------------------------------------------
extern "C" void kernel_launch(void* const* d_in, const int* in_sizes, int n_in,
                              void* d_out, int out_size, void* d_ws, size_t ws_size,
                              hipStream_t stream)
{
  (void)in_sizes; (void)n_in; (void)out_size; (void)ws_size;
  const float* embed = (const float*)d_in[0];
  const float* Wf  = (const float*)d_in[1];
  const float* bf_ = (const float*)d_in[2];
  const float* b_f = (const float*)d_in[3];
  const float* Wi  = (const float*)d_in[4];
  const float* bi_ = (const float*)d_in[5];
  const float* b_i = (const float*)d_in[6];
  const float* Wu  = (const float*)d_in[7];
  const float* bu_ = (const float*)d_in[8];
  const float* b_u = (const float*)d_in[9];
  const float* Wo  = (const float*)d_in[10];
  const float* bo_ = (const float*)d_in[11];
  const float* b_o = (const float*)d_in[12];
  const float* W1  = (const float*)d_in[13];
  const float* bl1 = (const float*)d_in[14];
  const float* W2  = (const float*)d_in[15];
  const float* bl2 = (const float*)d_in[16];
  const float* W3  = (const float*)d_in[17];
  const float* bl3 = (const float*)d_in[18];
  const float* W4  = (const float*)d_in[19];
  const float* bl4 = (const float*)d_in[20];

  char* ws = (char*)d_ws;
  _Float16* Wh   = (_Float16*)(ws);                 // 1,048,576 B
  float* bsum    = (float*)(ws + 1048576);          // 4 KB
  float* bias2   = (float*)(ws + 1052672);          // 4 KB
  float* cleaf2  = (float*)(ws + 1056768);          // 1 KB
  _Float16* hr   = (_Float16*)(ws + 1057792);       // 64 KB -> end 1,123,328
  _Float16* esum = (_Float16*)(ws + 1123328);       // 33,488,896 B -> 34,612,224
  _Float16* HsA  = (_Float16*)(ws + 34612224);      // 8,388,608 -> 43,000,832
  float* CsA     = (float*)(ws + 43000832);         // 16,777,216 -> 59,778,048
  _Float16* HsB  = (_Float16*)(ws + 59778048);      // 4,194,304 -> 63,972,352
  float* CsB     = (float*)(ws + 63972352);         // 8,388,608 -> 72,360,960

  prep_kernel<<<dim3(16), dim3(256), 0, stream>>>(bf_, b_f, bi_, b_i, bu_, b_u, bo_, b_o,
                                                  Wf, Wi, Wu, Wo, bsum, bias2, cleaf2);
  wcvt_kernel<<<dim3(512), dim3(256), 0, stream>>>(Wf, Wi, Wu, Wo, Wh);
  esum_kernel<<<dim3(64, 128), dim3(256), 0, stream>>>(embed, esum);

  _Float16* hbufs[2] = {HsA, HsB};
  float* cbufs[2] = {CsA, CsB};
  int pp = 0;
  const _Float16* hin = nullptr;
  const float* cin = cleaf2;
  for (int l = 8; l >= 0; --l) {
    const int leaf = (l == 8);
    const int fin = (l == 0);
    _Float16* hout = fin ? hr : hbufs[pp];
    float* cout = cbufs[pp];
    dim3 grid(1 << l, 8);
    level_kernel<<<grid, dim3(256), 0, stream>>>(hin, cin, esum, Wh,
                                                 leaf ? bias2 : bsum,
                                                 hout, cout, l, leaf, fin);
    hin = hbufs[pp];
    cin = cbufs[pp];
    pp ^= 1;
  }

  head_all_kernel<<<dim3(128), dim3(256), 0, stream>>>(hr, W1, bl1, W2, bl2, W3, bl3,
                                                       W4, bl4, (float*)d_out);
}

// Round 4
// 463.254 us; speedup vs baseline: 1.2964x; 1.0481x over previous
//
#include <hip/hip_runtime.h>

#define HD 256
#define KD 512

typedef _Float16 half8 __attribute__((ext_vector_type(8)));
typedef _Float16 half2v __attribute__((ext_vector_type(2)));
typedef _Float16 half4v __attribute__((ext_vector_type(4)));
typedef float floatx4 __attribute__((ext_vector_type(4)));
typedef float floatx2 __attribute__((ext_vector_type(2)));

__device__ __forceinline__ float sigmf_(float x) { return 1.f / (1.f + __expf(-x)); }
__device__ __forceinline__ float tanhf_(float x) {
  x = fminf(fmaxf(x, -15.f), 15.f);
  float e = __expf(2.f * x);
  return (e - 1.f) / (e + 1.f);
}

// ---------------------------------------------------------------------------
// prep (parallel, 16 blocks): gate bias sums, leaf csum (=2*c_leaf), and
// leaf-level folded bias: bias2[g][n] = bsum[g][n] + W_g[n][0:256]·(2*h_leaf)
// ---------------------------------------------------------------------------
__global__ void prep_kernel(const float* __restrict__ bf_, const float* __restrict__ b_f,
                            const float* __restrict__ bi_, const float* __restrict__ b_i,
                            const float* __restrict__ bu_, const float* __restrict__ b_u,
                            const float* __restrict__ bo_, const float* __restrict__ b_o,
                            const float* __restrict__ Wf, const float* __restrict__ Wi,
                            const float* __restrict__ Wu, const float* __restrict__ Wo,
                            float* __restrict__ bsum, float* __restrict__ bias2,
                            float* __restrict__ cleaf2)
{
  __shared__ float hl2[HD];
  __shared__ float part[64][4];
  const int t = threadIdx.x;
  float sf = bf_[t] + b_f[t];
  float si = bi_[t] + b_i[t];
  float su = bu_[t] + b_u[t];
  float so = bo_[t] + b_o[t];
  float ig = 1.f / (1.f + expf(-si));
  float uu = tanhf(su);
  float cl = ig * uu;
  float hl = (1.f / (1.f + expf(-so))) * tanhf(cl);
  hl2[t] = 2.f * hl;
  if (blockIdx.x == 0) {
    bsum[t] = sf; bsum[HD + t] = si; bsum[2 * HD + t] = su; bsum[3 * HD + t] = so;
    cleaf2[t] = cl + cl;
  }
  __syncthreads();
  const int g = blockIdx.x >> 2, q = blockIdx.x & 3;
  const int nl = t >> 2, kq = t & 3;
  const float* Wg = (g == 0) ? Wf : (g == 1) ? Wi : (g == 2) ? Wu : Wo;
  const float* w = Wg + (long)(q * 64 + nl) * KD + kq * 64;
  float s = 0.f;
  for (int k = 0; k < 64; k += 4) {
    floatx4 wv = *(const floatx4*)(w + k);
    floatx4 hv = *(const floatx4*)(&hl2[kq * 64 + k]);
    s += wv[0] * hv[0] + wv[1] * hv[1] + wv[2] * hv[2] + wv[3] * hv[3];
  }
  part[nl][kq] = s;
  __syncthreads();
  if (kq == 0) {
    const int n = q * 64 + nl;
    float tot = part[nl][0] + part[nl][1] + part[nl][2] + part[nl][3];
    float bg = (g == 0) ? (bf_[n] + b_f[n]) : (g == 1) ? (bi_[n] + b_i[n])
             : (g == 2) ? (bu_[n] + b_u[n]) : (bo_[n] + b_o[n]);
    bias2[g * HD + n] = bg + tot;
  }
}

// ---------------------------------------------------------------------------
// convert the 4 gate weights (fp32, [256][512]) to f16 packed [g][256][512]
// ---------------------------------------------------------------------------
__global__ void wcvt_kernel(const float* __restrict__ Wf, const float* __restrict__ Wi,
                            const float* __restrict__ Wu, const float* __restrict__ Wo,
                            _Float16* __restrict__ Wh)
{
  int idx = (blockIdx.x * 256 + threadIdx.x) * 4;
  int g = idx >> 17;
  int rem = idx & ((1 << 17) - 1);
  const float* src = (g == 0) ? Wf : (g == 1) ? Wi : (g == 2) ? Wu : Wo;
  floatx4 v = *(const floatx4*)(src + rem);
  half4v o;
  o[0] = (_Float16)v[0]; o[1] = (_Float16)v[1]; o[2] = (_Float16)v[2]; o[3] = (_Float16)v[3];
  *(half4v*)(Wh + idx) = o;
}

// ---------------------------------------------------------------------------
// esum: pre-materialized f16 embed pair-sums, parent-indexed.
// esum[b][p][c] = embed[b][2p+1][c] + embed[b][2p+2][c], p in [0,511).
// ---------------------------------------------------------------------------
__global__ void esum_kernel(const float* __restrict__ embed, _Float16* __restrict__ esum)
{
  const int task = blockIdx.x * 256 + threadIdx.x;
  if (task >= 511 * 32) return;
  const int b = blockIdx.y;
  const int p = task >> 5, g8 = task & 31;
  const float* e0 = embed + ((long)b * 1023 + 2 * p + 1) * 256 + g8 * 8;
  const float* e1 = e0 + 256;
  floatx4 x0 = *(const floatx4*)(e0);
  floatx4 x1 = *(const floatx4*)(e0 + 4);
  floatx4 y0 = *(const floatx4*)(e1);
  floatx4 y1 = *(const floatx4*)(e1 + 4);
  half8 s;
#pragma unroll
  for (int e = 0; e < 4; ++e) { s[e] = (_Float16)(x0[e] + y0[e]); s[4 + e] = (_Float16)(x1[e] + y1[e]); }
  *(half8*)(esum + ((long)b * 511 + p) * 256 + g8 * 8) = s;
}

// ---------------------------------------------------------------------------
// level kernel (narrow, R3-proven 485us): 128 rows x 32 cols x 4 gates,
// wave = 64r x 16c, grid (2^l, 8) XCD-aligned. Used for l <= 5 (small grids
// need 8 col-blocks for CU coverage). Unchanged from R3.
// ---------------------------------------------------------------------------
__global__ __launch_bounds__(256, 2)
void level_kernel(const _Float16* __restrict__ hsum_in,
                  const float* __restrict__ csum_in,
                  const _Float16* __restrict__ esum,
                  const _Float16* __restrict__ Wh,
                  const float* __restrict__ bias,
                  _Float16* __restrict__ hsum_out,
                  float* __restrict__ csum_out,
                  int l, int leaf, int fin)
{
  __shared__ _Float16 As[128][256];      // 64 KB, XOR-swizzled 16B granules

  const int cb = blockIdx.y;             // 0..7 col-block (XCD-aligned)
  const int m0 = blockIdx.x * 128;       // row-group
  const int t = threadIdx.x;
  const int wave = t >> 6;
  const int lane = t & 63;
  const int lm = lane & 15;
  const int quad = lane >> 4;
  const int rh = wave >> 1;              // row half (64 rows)
  const int ch = wave & 1;               // col half (16 cols)
  const int ncol = cb * 32 + ch * 16 + lm;

  floatx4 acc[4][4] = {};                // [mt][gate]

  const int srow0 = t >> 3;              // 0..31, +32 per pass
  const int sg = t & 7;                  // granule low bits

  const _Float16* wb = Wh + (long)ncol * KD + quad * 8;

  auto gemm_chunk = [&](int kbase) {
    half8 bcur[4], bnxt[4];
#pragma unroll
    for (int g = 0; g < 4; ++g)
      bcur[g] = *(const half8*)(wb + (long)g * HD * KD + kbase);
#pragma unroll
    for (int ks = 0; ks < 8; ++ks) {
      if (ks < 7) {
#pragma unroll
        for (int g = 0; g < 4; ++g)
          bnxt[g] = *(const half8*)(wb + (long)g * HD * KD + kbase + (ks + 1) * 32);
      }
      half8 afr[4];
#pragma unroll
      for (int mt = 0; mt < 4; ++mt) {
        int row = rh * 64 + mt * 16 + lm;
        afr[mt] = *(const half8*)(&As[row][(((ks * 4 + quad) ^ (row & 7)) * 8)]);
      }
#pragma unroll
      for (int mt = 0; mt < 4; ++mt)
#pragma unroll
        for (int g = 0; g < 4; ++g)
          acc[mt][g] = __builtin_amdgcn_mfma_f32_16x16x32_f16(afr[mt], bcur[g], acc[mt][g], 0, 0, 0);
#pragma unroll
      for (int g = 0; g < 4; ++g) bcur[g] = bnxt[g];
    }
  };

  const int msk = (1 << l) - 1;

  if (!leaf) {
#pragma unroll
    for (int p = 0; p < 4; ++p) {
      const int r = srow0 + 32 * p;
      const _Float16* src = hsum_in + (long)(m0 + r) * HD;
#pragma unroll
      for (int q = 0; q < 4; ++q) {
        int g8 = sg + 8 * q;
        *(half8*)(&As[r][((g8 ^ (r & 7)) * 8)]) = *(const half8*)(src + g8 * 8);
      }
    }
    __syncthreads();
    gemm_chunk(0);
    __syncthreads();
  }

  {
#pragma unroll
    for (int p = 0; p < 4; ++p) {
      const int r = srow0 + 32 * p;
      const int sm = m0 + r;
      const long erow = (long)(sm >> l) * 511 + msk + (sm & msk);
      const _Float16* src = esum + erow * HD;
#pragma unroll
      for (int q = 0; q < 4; ++q) {
        int g8 = sg + 8 * q;
        *(half8*)(&As[r][((g8 ^ (r & 7)) * 8)]) = *(const half8*)(src + g8 * 8);
      }
    }
  }
  __syncthreads();
  gemm_chunk(256);

  const float b0 = bias[ncol];
  const float b1 = bias[HD + ncol];
  const float b2 = bias[2 * HD + ncol];
  const float b3 = bias[3 * HD + ncol];
  const float clv = leaf ? csum_in[ncol] : 0.f;

#pragma unroll
  for (int mt = 0; mt < 4; ++mt) {
    const int mg0 = m0 + rh * 64 + mt * 16 + quad * 4;
    float hv[4], cvv[4];
#pragma unroll
    for (int e = 0; e < 4; ++e) {
      float cs = leaf ? clv : csum_in[(long)(mg0 + e) * HD + ncol];
      float zf = acc[mt][0][e] + b0;
      float zi = acc[mt][1][e] + b1;
      float zu = acc[mt][2][e] + b2;
      float zo = acc[mt][3][e] + b3;
      float f = sigmf_(zf), ig = sigmf_(zi), uu = tanhf_(zu), oo = sigmf_(zo);
      float cn = ig * uu + f * cs;
      cvv[e] = cn;
      hv[e] = oo * tanhf_(cn);
    }
    if (fin) {
#pragma unroll
      for (int e = 0; e < 4; ++e)
        hsum_out[(long)(mg0 + e) * HD + ncol] = (_Float16)hv[e];
    } else {
      const long pr = mg0 >> 1;
      hsum_out[pr * HD + ncol] = (_Float16)(hv[0] + hv[1]);
      hsum_out[(pr + 1) * HD + ncol] = (_Float16)(hv[2] + hv[3]);
      csum_out[pr * HD + ncol] = cvv[0] + cvv[1];
      csum_out[(pr + 1) * HD + ncol] = cvv[2] + cvv[3];
    }
  }
}

// ---------------------------------------------------------------------------
// level kernel WIDE (R4): 128 rows x 64 cols x 4 gates per block; wave =
// 128 rows x 16 cols (4 waves = 4 disjoint col-groups, no rh split).
//  - B (Wh) L2 traffic per output HALVES: every Wh element read exactly once
//    per block (narrow reads each twice via the rh pair).
//  - 32 MFMA per k-step per wave (vs 16) -> 2x latency cover per B prefetch.
//  - Barriers per output halve. A staging/LDS/swizzle identical (64 KB).
//  - acc[8][4] = 128 VGPR, total ~220, fits launch_bounds(256,2).
// Grid (2^l, 4), XCD-aligned (ids differ by 2^l = 0 mod 8). Used for
// l >= 6 only (grid >= 256 blocks keeps all CUs covered).
// ---------------------------------------------------------------------------
__global__ __launch_bounds__(256, 2)
void level_kernel_w(const _Float16* __restrict__ hsum_in,
                    const float* __restrict__ csum_in,
                    const _Float16* __restrict__ esum,
                    const _Float16* __restrict__ Wh,
                    const float* __restrict__ bias,
                    _Float16* __restrict__ hsum_out,
                    float* __restrict__ csum_out,
                    int l, int leaf)
{
  __shared__ _Float16 As[128][256];      // 64 KB, XOR-swizzled 16B granules

  const int cb = blockIdx.y;             // 0..3 col-block (64 cols)
  const int m0 = blockIdx.x * 128;       // row-group
  const int t = threadIdx.x;
  const int wave = t >> 6;               // 0..3 = col-group
  const int lane = t & 63;
  const int lm = lane & 15;
  const int quad = lane >> 4;
  const int ncol = cb * 64 + wave * 16 + lm;

  floatx4 acc[8][4] = {};                // [mt][gate] — static indices only

  const int srow0 = t >> 3;
  const int sg = t & 7;

  const _Float16* wb = Wh + (long)ncol * KD + quad * 8;

  auto gemm_chunk = [&](int kbase) {
    half8 bcur[4], bnxt[4];
#pragma unroll
    for (int g = 0; g < 4; ++g)
      bcur[g] = *(const half8*)(wb + (long)g * HD * KD + kbase);
#pragma unroll
    for (int ks = 0; ks < 8; ++ks) {
      if (ks < 7) {
#pragma unroll
        for (int g = 0; g < 4; ++g)
          bnxt[g] = *(const half8*)(wb + (long)g * HD * KD + kbase + (ks + 1) * 32);
      }
      half8 afr[8];
#pragma unroll
      for (int mt = 0; mt < 8; ++mt) {
        int row = mt * 16 + lm;
        afr[mt] = *(const half8*)(&As[row][(((ks * 4 + quad) ^ (row & 7)) * 8)]);
      }
#pragma unroll
      for (int mt = 0; mt < 8; ++mt)
#pragma unroll
        for (int g = 0; g < 4; ++g)
          acc[mt][g] = __builtin_amdgcn_mfma_f32_16x16x32_f16(afr[mt], bcur[g], acc[mt][g], 0, 0, 0);
#pragma unroll
      for (int g = 0; g < 4; ++g) bcur[g] = bnxt[g];
    }
  };

  const int msk = (1 << l) - 1;

  if (!leaf) {
#pragma unroll
    for (int p = 0; p < 4; ++p) {
      const int r = srow0 + 32 * p;
      const _Float16* src = hsum_in + (long)(m0 + r) * HD;
#pragma unroll
      for (int q = 0; q < 4; ++q) {
        int g8 = sg + 8 * q;
        *(half8*)(&As[r][((g8 ^ (r & 7)) * 8)]) = *(const half8*)(src + g8 * 8);
      }
    }
    __syncthreads();
    gemm_chunk(0);
    __syncthreads();
  }

  {
#pragma unroll
    for (int p = 0; p < 4; ++p) {
      const int r = srow0 + 32 * p;
      const int sm = m0 + r;
      const long erow = (long)(sm >> l) * 511 + msk + (sm & msk);
      const _Float16* src = esum + erow * HD;
#pragma unroll
      for (int q = 0; q < 4; ++q) {
        int g8 = sg + 8 * q;
        *(half8*)(&As[r][((g8 ^ (r & 7)) * 8)]) = *(const half8*)(src + g8 * 8);
      }
    }
  }
  __syncthreads();
  gemm_chunk(256);

  // ---------------- epilogue: fully in-lane ----------------
  const float b0 = bias[ncol];
  const float b1 = bias[HD + ncol];
  const float b2 = bias[2 * HD + ncol];
  const float b3 = bias[3 * HD + ncol];
  const float clv = leaf ? csum_in[ncol] : 0.f;

#pragma unroll
  for (int mt = 0; mt < 8; ++mt) {
    const int mg0 = m0 + mt * 16 + quad * 4;
    float hv[4], cvv[4];
#pragma unroll
    for (int e = 0; e < 4; ++e) {
      float cs = leaf ? clv : csum_in[(long)(mg0 + e) * HD + ncol];
      float zf = acc[mt][0][e] + b0;
      float zi = acc[mt][1][e] + b1;
      float zu = acc[mt][2][e] + b2;
      float zo = acc[mt][3][e] + b3;
      float f = sigmf_(zf), ig = sigmf_(zi), uu = tanhf_(zu), oo = sigmf_(zo);
      float cn = ig * uu + f * cs;
      cvv[e] = cn;
      hv[e] = oo * tanhf_(cn);
    }
    // wide is never the final level (l>=6): always pair-sum outputs
    const long pr = mg0 >> 1;
    hsum_out[pr * HD + ncol] = (_Float16)(hv[0] + hv[1]);
    hsum_out[(pr + 1) * HD + ncol] = (_Float16)(hv[2] + hv[3]);
    csum_out[pr * HD + ncol] = cvv[0] + cvv[1];
    csum_out[(pr + 1) * HD + ncol] = cvv[2] + cvv[3];
  }
}

// ---------------------------------------------------------------------------
// fused head: y=tanh(hr@W1+b1); y2=relu(hr@W2+b2)@W3+b3; out=relu((y+y2)@W4+b4)
// ---------------------------------------------------------------------------
__global__ void head_all_kernel(const _Float16* __restrict__ hr,
                                const float* __restrict__ W1, const float* __restrict__ bl1,
                                const float* __restrict__ W2, const float* __restrict__ bl2,
                                const float* __restrict__ W3, const float* __restrict__ bl3,
                                const float* __restrict__ W4, const float* __restrict__ bl4,
                                float* __restrict__ out)
{
  __shared__ float a[HD];
  __shared__ float t1s[HD];
  __shared__ float t2s[HD];
  int b = blockIdx.x, n = threadIdx.x;
  a[n] = (float)hr[b * HD + n];
  __syncthreads();
  {
    const float* w1 = W1 + n * HD;
    const float* w2 = W2 + n * HD;
    float s1 = bl1[n], s2 = bl2[n];
    for (int k = 0; k < HD; k += 4) {
      floatx4 av = *(const floatx4*)(&a[k]);
      floatx4 w1v = *(const floatx4*)(w1 + k);
      floatx4 w2v = *(const floatx4*)(w2 + k);
#pragma unroll
      for (int e = 0; e < 4; ++e) { s1 += av[e] * w1v[e]; s2 += av[e] * w2v[e]; }
    }
    t1s[n] = tanhf_(s1);
    t2s[n] = fmaxf(s2, 0.f);
  }
  __syncthreads();
  {
    const float* w3 = W3 + n * HD;
    float s3 = bl3[n];
    for (int k = 0; k < HD; k += 4) {
      floatx4 av = *(const floatx4*)(&t2s[k]);
      floatx4 wv = *(const floatx4*)(w3 + k);
#pragma unroll
      for (int e = 0; e < 4; ++e) s3 += av[e] * wv[e];
    }
    __syncthreads();
    a[n] = t1s[n] + s3;
  }
  __syncthreads();
  {
    const float* w4 = W4 + n * HD;
    float s4 = bl4[n];
    for (int k = 0; k < HD; k += 4) {
      floatx4 av = *(const floatx4*)(&a[k]);
      floatx4 wv = *(const floatx4*)(w4 + k);
#pragma unroll
      for (int e = 0; e < 4; ++e) s4 += av[e] * wv[e];
    }
    out[b * HD + n] = fmaxf(s4, 0.f);
  }
}

// ---------------------------------------------------------------------------
extern "C" void kernel_launch(void* const* d_in, const int* in_sizes, int n_in,
                              void* d_out, int out_size, void* d_ws, size_t ws_size,
                              hipStream_t stream)
{
  (void)in_sizes; (void)n_in; (void)out_size; (void)ws_size;
  const float* embed = (const float*)d_in[0];
  const float* Wf  = (const float*)d_in[1];
  const float* bf_ = (const float*)d_in[2];
  const float* b_f = (const float*)d_in[3];
  const float* Wi  = (const float*)d_in[4];
  const float* bi_ = (const float*)d_in[5];
  const float* b_i = (const float*)d_in[6];
  const float* Wu  = (const float*)d_in[7];
  const float* bu_ = (const float*)d_in[8];
  const float* b_u = (const float*)d_in[9];
  const float* Wo  = (const float*)d_in[10];
  const float* bo_ = (const float*)d_in[11];
  const float* b_o = (const float*)d_in[12];
  const float* W1  = (const float*)d_in[13];
  const float* bl1 = (const float*)d_in[14];
  const float* W2  = (const float*)d_in[15];
  const float* bl2 = (const float*)d_in[16];
  const float* W3  = (const float*)d_in[17];
  const float* bl3 = (const float*)d_in[18];
  const float* W4  = (const float*)d_in[19];
  const float* bl4 = (const float*)d_in[20];

  char* ws = (char*)d_ws;
  _Float16* Wh   = (_Float16*)(ws);                 // 1,048,576 B
  float* bsum    = (float*)(ws + 1048576);          // 4 KB
  float* bias2   = (float*)(ws + 1052672);          // 4 KB
  float* cleaf2  = (float*)(ws + 1056768);          // 1 KB
  _Float16* hr   = (_Float16*)(ws + 1057792);       // 64 KB -> end 1,123,328
  _Float16* esum = (_Float16*)(ws + 1123328);       // 33,488,896 B -> 34,612,224
  _Float16* HsA  = (_Float16*)(ws + 34612224);      // 8,388,608 -> 43,000,832
  float* CsA     = (float*)(ws + 43000832);         // 16,777,216 -> 59,778,048
  _Float16* HsB  = (_Float16*)(ws + 59778048);      // 4,194,304 -> 63,972,352
  float* CsB     = (float*)(ws + 63972352);         // 8,388,608 -> 72,360,960

  prep_kernel<<<dim3(16), dim3(256), 0, stream>>>(bf_, b_f, bi_, b_i, bu_, b_u, bo_, b_o,
                                                  Wf, Wi, Wu, Wo, bsum, bias2, cleaf2);
  wcvt_kernel<<<dim3(512), dim3(256), 0, stream>>>(Wf, Wi, Wu, Wo, Wh);
  esum_kernel<<<dim3(64, 128), dim3(256), 0, stream>>>(embed, esum);

  _Float16* hbufs[2] = {HsA, HsB};
  float* cbufs[2] = {CsA, CsB};
  int pp = 0;
  const _Float16* hin = nullptr;
  const float* cin = cleaf2;
  for (int l = 8; l >= 0; --l) {
    const int leaf = (l == 8);
    const int fin = (l == 0);
    _Float16* hout = fin ? hr : hbufs[pp];
    float* cout = cbufs[pp];
    if (l >= 6) {
      dim3 grid(1 << l, 4);
      level_kernel_w<<<grid, dim3(256), 0, stream>>>(hin, cin, esum, Wh,
                                                     leaf ? bias2 : bsum,
                                                     hout, cout, l, leaf);
    } else {
      dim3 grid(1 << l, 8);
      level_kernel<<<grid, dim3(256), 0, stream>>>(hin, cin, esum, Wh,
                                                   leaf ? bias2 : bsum,
                                                   hout, cout, l, leaf, fin);
    }
    hin = hbufs[pp];
    cin = cbufs[pp];
    pp ^= 1;
  }

  head_all_kernel<<<dim3(128), dim3(256), 0, stream>>>(hr, W1, bl1, W2, bl2, W3, bl3,
                                                       W4, bl4, (float*)d_out);
}